// Round 1
// 706.723 us; speedup vs baseline: 1.0691x; 1.0691x over previous
//
#include <hip/hip_runtime.h>
#include <hip/hip_bf16.h>

#define E_ 160
#define CAP_ 120
#define S_ 3200
#define H_ 2048
#define I_ 192
#define K_ 6
#define MP_ 128   // padded rows per expert (CAP=120 -> 128)

typedef __attribute__((ext_vector_type(8))) short short8;
typedef __attribute__((ext_vector_type(4))) float f32x4;

// pack two fp32 -> two bf16 (truncate/RTZ) in one v_perm_b32
__device__ __forceinline__ unsigned pack2bf(float a, float b) {
  return __builtin_amdgcn_perm(__float_as_uint(b), __float_as_uint(a), 0x07060302u);
}
__device__ __forceinline__ short f2bf1(float a) {
  return (short)(__float_as_uint(a) >> 16);
}
__device__ __forceinline__ float bf2f(short s) {
  return __uint_as_float(((unsigned)(unsigned short)s) << 16);
}
// T2 swizzle: byte address within a [row][64]-bf16 tile (128B rows),
// XOR the 16B-slot index with (row&7) -> kills the 16-way ds_read_b128 conflict
__device__ __forceinline__ int swz(int row, int inrow_byte) {
  return row * 128 + (inrow_byte ^ ((row & 7) << 4));
}

// ---------------- kernel 1: fused gather + gate/up GEMM + silu --------------
// grid: E*3 blocks (expert e, i-tile of 64), XCD-swizzled so the 3 tiles of an
// expert share one XCD's L2 (hidden rows read once from L3). C tile 128x128:
// cols 0-63 gate, 64-127 up. 4 waves 2x2; wave tile 64x64. BK=64, 32 K-iters.
// T14 pipeline: reg-prefetch next tile, double-buffered LDS, ONE raw barrier
// per iter (no vmcnt drain -> loads stay in flight across the barrier).
__global__ __launch_bounds__(256, 2) void k_gateup(
    const float* __restrict__ hidden, const int* __restrict__ tok,
    const float* __restrict__ gw, const float* __restrict__ uw,
    short* __restrict__ hb)
{
  __shared__ __align__(16) char smem[65536];  // A0|B0|A1|B1, 16KB each

  int bid = blockIdx.x;
  int lb = (bid & 7) * 60 + (bid >> 3);       // bijective XCD swizzle (480=8*60)
  int e = lb / 3, t = lb - e * 3;
  int i0 = t * 64;
  int tid = threadIdx.x;
  int lane = tid & 63, w = tid >> 6;
  int wr = w >> 1, wc = w & 1;
  int lrow = lane & 15, lq = lane >> 4;

  // staging map: chunk c in [0,4): row = rr + 32c, cols cq*8 .. cq*8+7
  int rr = tid >> 3;
  int cq = tid & 7;

  int aoff[4];      // element offsets into hidden (gathered rows)
  int arowok[4];
#pragma unroll
  for (int c = 0; c < 4; ++c) {
    int row = rr + 32 * c;
    int ok = (row < CAP_);
    int tk = ok ? tok[e * CAP_ + row] : 0;
    aoff[c] = tk * H_ + cq * 8;
    arowok[c] = ok;
  }
  int boff[4];      // c<2: gate rows rr+32c ; c>=2: up rows rr+32c-64
#pragma unroll
  for (int c = 0; c < 4; ++c) {
    int row = rr + 32 * c;
    int wrow = (c < 2) ? row : row - 64;
    boff[c] = (e * I_ + i0 + wrow) * H_ + cq * 8;
  }

  f32x4 acc[4][4] = {};
  float4 av[4][2], bv[4][2];

  auto gload = [&](int k0) {
#pragma unroll
    for (int c = 0; c < 4; ++c) {
      const float* ap = hidden + aoff[c] + k0;
      av[c][0] = *(const float4*)ap;
      av[c][1] = *(const float4*)(ap + 4);
      const float* bp = ((c < 2) ? gw : uw) + boff[c] + k0;
      bv[c][0] = *(const float4*)bp;
      bv[c][1] = *(const float4*)(bp + 4);
    }
  };

  gload(0);

  for (int kk = 0; kk < H_ / 64; ++kk) {
    char* As = smem + ((kk & 1) << 15);
    char* Bs = As + 16384;
    // pack + LDS write (first use of av/bv -> compiler inserts vmcnt waits)
#pragma unroll
    for (int c = 0; c < 4; ++c) {
      int row = rr + 32 * c;
      int4 va;
      va.x = (int)pack2bf(av[c][0].x, av[c][0].y);
      va.y = (int)pack2bf(av[c][0].z, av[c][0].w);
      va.z = (int)pack2bf(av[c][1].x, av[c][1].y);
      va.w = (int)pack2bf(av[c][1].z, av[c][1].w);
      if (!arowok[c]) va = make_int4(0, 0, 0, 0);
      *(int4*)(As + swz(row, cq * 16)) = va;
      int4 vb;
      vb.x = (int)pack2bf(bv[c][0].x, bv[c][0].y);
      vb.y = (int)pack2bf(bv[c][0].z, bv[c][0].w);
      vb.z = (int)pack2bf(bv[c][1].x, bv[c][1].y);
      vb.w = (int)pack2bf(bv[c][1].z, bv[c][1].w);
      *(int4*)(Bs + swz(row, cq * 16)) = vb;
    }
    // issue NEXT tile's global loads now; they stay in flight across the
    // barrier (no vmcnt drain) and land during the MFMA phase + next pack.
    if (kk + 1 < H_ / 64) gload((kk + 1) * 64);
    __builtin_amdgcn_sched_barrier(0);          // pin loads above the barrier
    asm volatile("s_waitcnt lgkmcnt(0)" ::: "memory");  // ds_writes visible
    __builtin_amdgcn_s_barrier();
#pragma unroll
    for (int ks = 0; ks < 2; ++ks) {
      short8 a[4], bb[4];
#pragma unroll
      for (int tr = 0; tr < 4; ++tr) {
        int row = wr * 64 + tr * 16 + lrow;
        a[tr] = *(const short8*)(As + swz(row, ks * 64 + lq * 16));
      }
#pragma unroll
      for (int tc = 0; tc < 4; ++tc) {
        int row = wc * 64 + tc * 16 + lrow;
        bb[tc] = *(const short8*)(Bs + swz(row, ks * 64 + lq * 16));
      }
      __builtin_amdgcn_s_setprio(1);
#pragma unroll
      for (int tr = 0; tr < 4; ++tr)
#pragma unroll
        for (int tc = 0; tc < 4; ++tc)
          acc[tr][tc] = __builtin_amdgcn_mfma_f32_16x16x32_bf16(
              a[tr], bb[tc], acc[tr][tc], 0, 0, 0);
      __builtin_amdgcn_s_setprio(0);
    }
  }
  __syncthreads();

  // epilogue: waves wc=0 hold gate (cols 0-63), wc=1 hold up (cols 64-127).
  // Exchange g via LDS [2][64][68] fp32 (overlays smem), then h = silu(g)*u.
  float* exch = (float*)smem;
  if (wc == 0) {
#pragma unroll
    for (int tr = 0; tr < 4; ++tr)
#pragma unroll
      for (int tc = 0; tc < 4; ++tc)
#pragma unroll
        for (int rg = 0; rg < 4; ++rg) {
          int lr = tr * 16 + lq * 4 + rg;
          int lcol = tc * 16 + lrow;
          exch[(wr * 64 + lr) * 68 + lcol] = acc[tr][tc][rg];
        }
  }
  __syncthreads();
  if (wc == 1) {
#pragma unroll
    for (int tr = 0; tr < 4; ++tr)
#pragma unroll
      for (int tc = 0; tc < 4; ++tc)
#pragma unroll
        for (int rg = 0; rg < 4; ++rg) {
          int lr = tr * 16 + lq * 4 + rg;
          int lcol = tc * 16 + lrow;
          float g = exch[(wr * 64 + lr) * 68 + lcol];
          float u = acc[tr][tc][rg];
          float hv = g / (1.f + __expf(-g)) * u;
          hb[((size_t)e * MP_ + wr * 64 + lr) * I_ + i0 + lcol] = f2bf1(hv);
        }
  }
}

// ---------------- kernel 2: down GEMM, o -> bf16 compact [E*120][H] ---------
// grid: E*16 (expert e, 128-wide h-tile), XCD-swizzled so the 16 tiles of an
// expert share one XCD's L2 (hb 48KB/expert read once). BK=64, 3 K-iters.
__global__ __launch_bounds__(256) void k_down(
    const short* __restrict__ hb, const float* __restrict__ dw,
    short* __restrict__ ob)
{
  __shared__ __align__(16) char smem2[32768];
  char* As = smem2;
  char* Bs = smem2 + 16384;
  int bid = blockIdx.x;
  int lb = (bid & 7) * 320 + (bid >> 3);      // bijective XCD swizzle (2560=8*320)
  int e = lb >> 4, t = lb & 15;
  int n0 = t * 128;
  int tid = threadIdx.x;
  int lane = tid & 63, w = tid >> 6;
  int wr = w >> 1, wc = w & 1;
  int lrow = lane & 15, lq = lane >> 4;

  f32x4 acc[4][4] = {};

  for (int kk = 0; kk < 3; ++kk) {
    int k0 = kk * 64;
#pragma unroll
    for (int r = 0; r < 4; ++r) {
      int q = r * 256 + tid;
      int row = q >> 3, cc = q & 7;
      int4 v = *(const int4*)(hb + ((size_t)e * MP_ + row) * I_ + k0 + cc * 8);
      *(int4*)(As + swz(row, cc * 16)) = v;
    }
#pragma unroll
    for (int r = 0; r < 8; ++r) {
      int p = r * 256 + tid;
      int row = p >> 4, cc = p & 15;
      const float* srcw = dw + ((size_t)e * H_ + n0 + row) * I_ + k0 + cc * 4;
      float4 f = *(const float4*)srcw;
      uint2 pv;
      pv.x = pack2bf(f.x, f.y); pv.y = pack2bf(f.z, f.w);
      *(uint2*)(Bs + swz(row, cc * 8)) = pv;
    }
    __syncthreads();
#pragma unroll
    for (int ks = 0; ks < 2; ++ks) {
      short8 a[4], bb[4];
#pragma unroll
      for (int tr = 0; tr < 4; ++tr) {
        int row = wr * 64 + tr * 16 + lrow;
        a[tr] = *(const short8*)(As + swz(row, ks * 64 + lq * 16));
      }
#pragma unroll
      for (int tc = 0; tc < 4; ++tc) {
        int row = wc * 64 + tc * 16 + lrow;
        bb[tc] = *(const short8*)(Bs + swz(row, ks * 64 + lq * 16));
      }
#pragma unroll
      for (int tr = 0; tr < 4; ++tr)
#pragma unroll
        for (int tc = 0; tc < 4; ++tc)
          acc[tr][tc] = __builtin_amdgcn_mfma_f32_16x16x32_bf16(
              a[tr], bb[tc], acc[tr][tc], 0, 0, 0);
    }
    __syncthreads();
  }

  // store compact rows c < 120
#pragma unroll
  for (int tr = 0; tr < 4; ++tr) {
#pragma unroll
    for (int rg = 0; rg < 4; ++rg) {
      int c = wr * 64 + tr * 16 + lq * 4 + rg;
      if (c < CAP_) {
#pragma unroll
        for (int tc = 0; tc < 4; ++tc) {
          int col = n0 + wc * 64 + tc * 16 + lrow;
          ob[((size_t)e * CAP_ + c) * H_ + col] = f2bf1(acc[tr][tc][rg]);
        }
      }
    }
  }
}

// ---------------- kernel 3: gather-combine -----------------------------------
// grid: S blocks, 256 thr; thread covers 8 cols of one token s.
__global__ __launch_bounds__(256) void k_combine(
    const short* __restrict__ ob, const int* __restrict__ re_index,
    const float* __restrict__ topk, const float* __restrict__ shared_out,
    float* __restrict__ out)
{
  int s = blockIdx.x;
  int c0 = threadIdx.x * 8;
  const float* sh = shared_out + (size_t)s * H_ + c0;
  float4 s0 = *(const float4*)sh;
  float4 s1 = *(const float4*)(sh + 4);
  float r[8] = {s0.x, s0.y, s0.z, s0.w, s1.x, s1.y, s1.z, s1.w};
#pragma unroll
  for (int k = 0; k < K_; ++k) {
    int p = k * S_ + s;
    int idx = re_index[p];
    float wgt = topk[p];
    const short* row = ob + (size_t)idx * H_ + c0;
    short8 v = *(const short8*)row;
#pragma unroll
    for (int j = 0; j < 8; ++j) r[j] += wgt * bf2f(v[j]);
  }
  float* o = out + (size_t)s * H_ + c0;
  float4 o0, o1;
  o0.x = r[0]; o0.y = r[1]; o0.z = r[2]; o0.w = r[3];
  o1.x = r[4]; o1.y = r[5]; o1.z = r[6]; o1.w = r[7];
  *(float4*)o = o0;
  *(float4*)(o + 4) = o1;
}

extern "C" void kernel_launch(void* const* d_in, const int* in_sizes, int n_in,
                              void* d_out, int out_size, void* d_ws, size_t ws_size,
                              hipStream_t stream) {
  const float* hidden     = (const float*)d_in[0];
  const int*   tok        = (const int*)d_in[1];
  const int*   re_index   = (const int*)d_in[2];
  const float* topk       = (const float*)d_in[3];
  const float* shared_out = (const float*)d_in[4];
  const float* gw         = (const float*)d_in[5];
  const float* uw         = (const float*)d_in[6];
  const float* dw         = (const float*)d_in[7];
  float* out = (float*)d_out;

  char* ws = (char*)d_ws;
  short* hb = (short*)ws;                                   // [E][128][I] bf16, 7.9 MB
  short* ob = (short*)(ws + (size_t)E_ * MP_ * I_ * 2);     // [E*120][H] bf16, 78.6 MB

  hipLaunchKernelGGL(k_gateup,  dim3(E_ * 3),  dim3(256), 0, stream, hidden, tok, gw, uw, hb);
  hipLaunchKernelGGL(k_down,    dim3(E_ * 16), dim3(256), 0, stream, hb, dw, ob);
  hipLaunchKernelGGL(k_combine, dim3(S_),      dim3(256), 0, stream, ob, re_index, topk, shared_out, out);
}